// Round 2
// 171.418 us; speedup vs baseline: 1.0196x; 1.0196x over previous
//
#include <hip/hip_runtime.h>

// F=32 fields, B=8192 batch, D=64.
// out[b, r*64+c] = s[b,r]*s[b,c], s[b,d] = sum_f in[f,b,0,d].
// Memory-bound: 64 MiB read + 128 MiB write -> ~30 us floor at 6.3 TB/s.
//
// Decomposition: 1 wave owns 4 consecutive samples.
//   lane = lb*16 + dv,  lb = sample-in-wave (0..3), dv = float4 chunk of D (0..15)
//   Stage 1: acc[lane] = sum_f in4[(f*B + b)*16 + dv] -- for fixed f a wave's 64
//            lanes touch a contiguous 1 KiB segment (perfect coalescing), and the
//            field-sum lives entirely in one lane: NO cross-lane reduction.
//   Stage 2: out4[idx4], idx4 = it*64+lane -> r = it*4+lb, c4 = dv. sc is
//            lane-invariant across `it` (hoisted); s[r] is one scalar LDS read.
//            Stores are contiguous 1 KiB per wave-instruction.
//
// R1/R2 change vs previous best (174.8 us): stores are now PLAIN (write-back)
// instead of __builtin_nontemporal_store. Rationale: MI355X's 256 MiB
// Infinity Cache is memory-side; a 128 MiB output stream fits and can be
// absorbed at cache speed, while the nt hint forces no-allocate drain at raw
// HBM write bandwidth (the 6.6 TB/s rocclr fill kernel uses plain stores).
// Loads stay nontemporal: read-once streams should not pollute L2.
// (R2 is a resubmit of R1 — the R1 bench died in container acquisition,
// giving zero measurement signal.)

#define NF 32
#define NB 8192
#define ND 64

typedef float f4 __attribute__((ext_vector_type(4)));

__global__ __launch_bounds__(256) void opnn_outer_kernel(
    const float* __restrict__ in, float* __restrict__ out) {
    const int tid  = threadIdx.x;
    const int w    = tid >> 6;        // wave in block: 0..3
    const int lane = tid & 63;
    const int lb   = lane >> 4;       // sample within wave: 0..3
    const int dv   = lane & 15;       // float4 index within D
    const int s_local = w * 4 + lb;   // sample within block: 0..15
    const int b = blockIdx.x * 16 + s_local;

    // ---- Stage 1: per-lane field sum (no reduction needed) ----
    const f4* __restrict__ in4 = (const f4*)in;
    const size_t base = (size_t)b * (ND / 4) + dv;
    f4 acc = (f4)0.f;
    #pragma unroll
    for (int f = 0; f < NF; ++f) {
        f4 v = __builtin_nontemporal_load(&in4[base + (size_t)f * NB * (ND / 4)]);
        acc += v;
    }

    __shared__ f4 sh[16][16];         // [sample-in-block][dv]
    sh[s_local][dv] = acc;
    __syncthreads();

    // ---- Stage 2: outer product, 1 KiB contiguous per store instruction ----
    const float* shf = (const float*)sh;
    #pragma unroll
    for (int ss = 0; ss < 4; ++ss) {
        const int sidx = w * 4 + ss;                       // sample within block
        const f4 sc = sh[sidx][dv];                        // column vec, hoisted
        f4* __restrict__ outp =
            (f4*)(out + ((size_t)blockIdx.x * 16 + sidx) * (ND * ND));
        #pragma unroll
        for (int it = 0; it < 16; ++it) {
            const int r = it * 4 + lb;                     // row 0..63
            const float sr = shf[sidx * 64 + r];           // 4 addrs, 16x broadcast
            f4 v = sr * sc;
            outp[it * 64 + lane] = v;                      // plain write-back store
        }
    }
}

extern "C" void kernel_launch(void* const* d_in, const int* in_sizes, int n_in,
                              void* d_out, int out_size, void* d_ws, size_t ws_size,
                              hipStream_t stream) {
    const float* in = (const float*)d_in[0];
    float* out = (float*)d_out;
    opnn_outer_kernel<<<NB / 16, 256, 0, stream>>>(in, out);
}